// Round 21
// baseline (86.318 us; speedup 1.0000x reference)
//
#include <hip/hip_runtime.h>

typedef unsigned short u16;
typedef float f32x4 __attribute__((ext_vector_type(4)));
typedef __bf16 bf16x4 __attribute__((ext_vector_type(4)));
typedef __bf16 bf16x8 __attribute__((ext_vector_type(8)));

#define B_ 8
#define N_ 4096
#define C_ 256
#define NKV 256
// softmax scale folded into k: 1/sqrt(32) * log2(e)
#define CEXP 0.25506604f

__device__ inline u16 f2bf(float f) {
    union { float f; unsigned u; } v; v.f = f;
    unsigned r = v.u + 0x7FFF + ((v.u >> 16) & 1);
    return (u16)(r >> 16);
}

// async global->LDS, 16B per lane (dest linear-in-lane with 16B stride)
__device__ inline void gload16(const void* g, void* l) {
    __builtin_amdgcn_global_load_lds(
        (const __attribute__((address_space(1))) void*)g,
        (__attribute__((address_space(3))) void*)l, 16, 0, 0);
}

// ---------------- prep (merged): x -> bf16 xb; weights -> bf16 ----------------
__global__ __launch_bounds__(256) void prep_all(
    const float* __restrict__ x, u16* __restrict__ xb,
    const float* __restrict__ qw, const float* __restrict__ kvw,
    const float* __restrict__ pw, const float* __restrict__ srw,
    u16* __restrict__ wqb, u16* __restrict__ wkv, u16* __restrict__ wp, u16* __restrict__ wsr)
{
    // x part: one float4 per thread over 8192x256 threads
    size_t base = ((size_t)blockIdx.x * 256 + threadIdx.x) * 4;
    float4 v = *(const float4*)(x + base);
    ushort4 o;
    o.x = f2bf(v.x); o.y = f2bf(v.y); o.z = f2bf(v.z); o.w = f2bf(v.w);
    *(ushort4*)(xb + base) = o;

    // weight part (strided over the whole grid)
    int t = blockIdx.x * 256 + threadIdx.x;
    int stride = gridDim.x * 256;
    for (int i = t; i < 65536; i += stride) { wqb[i] = f2bf(qw[i]); wp[i] = f2bf(pw[i]); }
    for (int i = t; i < 131072; i += stride) wkv[i] = f2bf(kvw[i]);
    // wsr[o][(kh*4+kw)*256 + ci] = srw[o][ci][kh][kw]
    for (int i = t; i < 1048576; i += stride) {
        int oo = i >> 12, kk = i & 4095;
        int ci = kk & 255, khkw = kk >> 8;
        wsr[i] = f2bf(srw[(size_t)(oo * 256 + ci) * 16 + khkw]);
    }
}

// ---------------- 128x128 bf16 MFMA GEMM body, BK=64 double-depth staging ----------------
// out = A[M,K] @ Bt[N,K]^T (+bias). LDS per tile: two [128][32] sub-buffers (16 KB each
// operand). Chunk c (0..1023, 16B each) -> byte c*16 (LINEAR dest for global_load_lds);
// c>>9 selects the 32-k half (s), (c&511)>>2 the row, c&3 the 8-col piece. The (s,p2)
// split is folded into the per-chunk GLOBAL source. Halves barrier drains vs BK=32.
// kchunk must be a multiple of 64.
// OUTMODE: 0 = f32 out + bias, 1 = bf16 out + bias, 2 = f32 split-K partial (no bias)
// IM2COL: A is xb [B*N][C]; logical A-row = b*256 + hp*16 + wp, k = (kh*4+kw)*256 + c;
//         every 64-aligned k-span stays inside one (kh,kw) plane (k0,kk multiples of 64).
template<int OUTMODE, bool IM2COL>
__device__ __forceinline__ void gemm_body(
    u16* As, u16* Bs,
    const u16* __restrict__ A, const u16* __restrict__ Bt,
    const float* __restrict__ bias, void* __restrict__ outp,
    int M, int Nn, int K, int kchunk, int bm, int bn, int bz)
{
    const int tid = threadIdx.x;
    const int k0 = bz * kchunk;
    const int wid = tid >> 6, lane = tid & 63;
    const int wr = wid >> 1, wc = wid & 1;
    const int lrow = lane & 15, lkg = lane >> 4;

    f32x4 acc[4][4] = {};

    // 4 chunks per thread per operand: c_j = tid + 256*j
    const u16 *aS[4], *bS[4];
#pragma unroll
    for (int j = 0; j < 4; ++j) {
        const int c = tid + 256 * j;
        const int s = c >> 9, r = (c & 511) >> 2, p2 = c & 3;
        const int colo = s * 32 + p2 * 8;
        if constexpr (IM2COL) {
            const int g = bm * 128 + r;
            const int bb = g >> 8, p = g & 255;
            aS[j] = A + (size_t)(bb * 4096 + (p >> 4) * 256 + (p & 15) * 4) * 256 + colo;
        } else {
            aS[j] = A + (size_t)(bm * 128 + r) * K + k0 + colo;
        }
        bS[j] = Bt + (size_t)(bn * 128 + r) * K + k0 + colo;
    }

    for (int kk = 0; kk < kchunk; kk += 64) {
        int aoff;
        if constexpr (IM2COL) {
            const int K0 = k0 + kk;
            const int khkw = K0 >> 8;
            aoff = ((khkw >> 2) * 64 + (khkw & 3)) * 256 + (K0 & 255);
        } else {
            aoff = kk;
        }
#pragma unroll
        for (int j = 0; j < 4; ++j) {
            gload16(aS[j] + aoff, As + tid * 8 + j * 2048);
            gload16(bS[j] + kk,  Bs + tid * 8 + j * 2048);
        }
        __syncthreads();
#pragma unroll
        for (int ks = 0; ks < 2; ++ks) {
            bf16x8 af[4], bff[4];
#pragma unroll
            for (int i = 0; i < 4; ++i) {
                af[i]  = *(const bf16x8*)(As + ks * 4096 + (wr * 64 + i * 16 + lrow) * 32 + lkg * 8);
                bff[i] = *(const bf16x8*)(Bs + ks * 4096 + (wc * 64 + i * 16 + lrow) * 32 + lkg * 8);
            }
#pragma unroll
            for (int i = 0; i < 4; ++i)
#pragma unroll
                for (int j = 0; j < 4; ++j)
                    acc[i][j] = __builtin_amdgcn_mfma_f32_16x16x32_bf16(af[i], bff[j], acc[i][j], 0, 0, 0);
        }
        __syncthreads();
    }

    const int row0 = bm * 128 + wr * 64;
    const int col0 = bn * 128 + wc * 64;
    if constexpr (OUTMODE == 2) {
        float* o = (float*)outp + (size_t)bz * M * Nn;
#pragma unroll
        for (int i = 0; i < 4; ++i)
#pragma unroll
            for (int j = 0; j < 4; ++j)
#pragma unroll
                for (int reg = 0; reg < 4; ++reg)
                    o[(size_t)(row0 + i * 16 + lkg * 4 + reg) * Nn + col0 + j * 16 + lrow] = acc[i][j][reg];
    } else {
#pragma unroll
        for (int j = 0; j < 4; ++j) {
            const int col = col0 + j * 16 + lrow;
            float bv = bias[col];
#pragma unroll
            for (int i = 0; i < 4; ++i)
#pragma unroll
                for (int reg = 0; reg < 4; ++reg) {
                    const size_t idx = (size_t)(row0 + i * 16 + lkg * 4 + reg) * Nn + col;
                    const float val = acc[i][j][reg] + bv;
                    if constexpr (OUTMODE == 1) ((u16*)outp)[idx] = f2bf(val);
                    else                        ((float*)outp)[idx] = val;
                }
        }
    }
}

// standalone GEMM wrapper (output projection); 3 blocks/CU (96 KB LDS, ~110 VGPR < 170 cap)
template<int OUTMODE, bool IM2COL>
__global__ __launch_bounds__(256, 3) void gemm128(
    const u16* __restrict__ A, const u16* __restrict__ Bt,
    const float* __restrict__ bias, void* __restrict__ outp,
    int M, int Nn, int K, int kchunk)
{
    __shared__ __align__(16) u16 As[128 * 64];
    __shared__ __align__(16) u16 Bs[128 * 64];
    gemm_body<OUTMODE, IM2COL>(As, Bs, A, Bt, bias, outp, M, Nn, K, kchunk,
                               blockIdx.x, blockIdx.y, blockIdx.z);
}

// ---------------- fused launch: conv GEMM (split-K x4, im2col) + q projection -------------
// ids 0..127: conv (16 bm x 2 bn x 4 z, K=1024 each). ids 128..639: q proj (256 bm x 2 bn).
// All 640 blocks co-resident at 3/CU (768 slots) -> conv long-poles (16 BK-64 iters ~5us)
// are covered by q-block work; split-K x4 halves part traffic vs x8 (8.4 MB vs 16.8 MB).
// No cross-block sync (round-12 lesson: dispatch order is undefined).
__global__ __launch_bounds__(256, 3) void fused_convq(
    const u16* __restrict__ xb, const u16* __restrict__ wsr, float* __restrict__ part,
    const u16* __restrict__ wqb, const float* __restrict__ qb, u16* __restrict__ qbuf)
{
    __shared__ __align__(16) u16 As[128 * 64];
    __shared__ __align__(16) u16 Bs[128 * 64];
    const int id = blockIdx.x;
    if (id < 128) {
        const int z = id & 3, t = id >> 2;
        gemm_body<2, true>(As, Bs, xb, wsr, nullptr, part,
                           2048, 256, 4096, 1024, t >> 1, t & 1, z);
    } else {
        const int qid = id - 128;
        gemm_body<1, false>(As, Bs, xb, wqb, qb, qbuf,
                            32768, 256, 256, 256, qid >> 1, qid & 1, 0);
    }
}

// ---------------- LN over conv partial sums: xsr = LN(sum_z part + sr_b) -> bf16 ----------------
__global__ __launch_bounds__(256) void ln_kernel(
    const float* __restrict__ part, const float* __restrict__ srb,
    const float* __restrict__ g, const float* __restrict__ bb, u16* __restrict__ out)
{
    const int row = blockIdx.x, c = threadIdx.x;
    const size_t idx = (size_t)row * 256 + c;
    float v = srb[c];
#pragma unroll
    for (int z = 0; z < 4; ++z) v += part[idx + (size_t)z * 524288];
    float s = v;
#pragma unroll
    for (int m = 1; m < 64; m <<= 1) s += __shfl_xor(s, m);
    __shared__ float red[4];
    if ((c & 63) == 0) red[c >> 6] = s;
    __syncthreads();
    float tot = red[0] + red[1] + red[2] + red[3];
    float mu = tot * (1.0f / 256.0f);
    float d = v - mu;
    float s2 = d * d;
#pragma unroll
    for (int m = 1; m < 64; m <<= 1) s2 += __shfl_xor(s2, m);
    __syncthreads();
    if ((c & 63) == 0) red[c >> 6] = s2;
    __syncthreads();
    float var = (red[0] + red[1] + red[2] + red[3]) * (1.0f / 256.0f);
    out[idx] = f2bf(d * rsqrtf(var + 1e-5f) * g[c] + bb[c]);
}

// ---------------- kv projection: 64x64 tiles, BK=64 staging, k-half pre-scaled ------------
// grid (32, 8) = 256 blocks. Two [64][32] sub-buffers per operand; chunk c (0..511) ->
// byte c*16 linear; c>>8 = 32-k half, (c&255)>>2 = row, c&3 = piece.
__global__ __launch_bounds__(256, 2) void gemm64_kv(
    const u16* __restrict__ A, const u16* __restrict__ Bt,
    const float* __restrict__ bias, u16* __restrict__ outp)
{
    __shared__ __align__(16) u16 As[64 * 64];
    __shared__ __align__(16) u16 Bs[64 * 64];
    const int tid = threadIdx.x, bm = blockIdx.x, bn = blockIdx.y;
    const int wid = tid >> 6, lane = tid & 63;
    const int wr = wid >> 1, wc = wid & 1;
    const int lrow = lane & 15, lkg = lane >> 4;

    f32x4 acc[2][2] = {};
    const u16 *aS[2], *bS[2];
#pragma unroll
    for (int j = 0; j < 2; ++j) {
        const int c = tid + 256 * j;
        const int s = c >> 8, r = (c & 255) >> 2, p2 = c & 3;
        const int colo = s * 32 + p2 * 8;
        aS[j] = A  + (size_t)(bm * 64 + r) * 256 + colo;
        bS[j] = Bt + (size_t)(bn * 64 + r) * 256 + colo;
    }

    for (int kk = 0; kk < 256; kk += 64) {
#pragma unroll
        for (int j = 0; j < 2; ++j) {
            gload16(aS[j] + kk, As + tid * 8 + j * 2048);
            gload16(bS[j] + kk, Bs + tid * 8 + j * 2048);
        }
        __syncthreads();
#pragma unroll
        for (int ks = 0; ks < 2; ++ks) {
            bf16x8 af[2], bf2[2];
#pragma unroll
            for (int i = 0; i < 2; ++i) {
                af[i]  = *(const bf16x8*)(As + ks * 2048 + (wr * 32 + i * 16 + lrow) * 32 + lkg * 8);
                bf2[i] = *(const bf16x8*)(Bs + ks * 2048 + (wc * 32 + i * 16 + lrow) * 32 + lkg * 8);
            }
#pragma unroll
            for (int i = 0; i < 2; ++i)
#pragma unroll
                for (int j = 0; j < 2; ++j)
                    acc[i][j] = __builtin_amdgcn_mfma_f32_16x16x32_bf16(af[i], bf2[j], acc[i][j], 0, 0, 0);
        }
        __syncthreads();
    }

    const int row0 = bm * 64 + wr * 32;
    const int col0 = bn * 64 + wc * 32;
#pragma unroll
    for (int j = 0; j < 2; ++j) {
        const int col = col0 + j * 16 + lrow;
        const float bv = bias[col];
        const float sc = (col < 256) ? CEXP : 1.0f;
#pragma unroll
        for (int i = 0; i < 2; ++i)
#pragma unroll
            for (int reg = 0; reg < 4; ++reg)
                outp[(size_t)(row0 + i * 16 + lkg * 4 + reg) * 512 + col] =
                    f2bf((acc[i][j][reg] + bv) * sc);
    }
}

// ---------------- fused attention v10: 4 q-tiles per staged K/V; XCD-aware 1D grid --------
// grid 1024 = exactly one residency wave (256 CU x 4 blocks). logical = (bid&7)*128+bid>>3
// (each XCD owns one batch b; 1024%8==0). Per block: stage K[256][32] (XOR-swizzled via
// pre-swizzled global source) + V^T[32][264] ONCE, then 4 sequential 64-row q-tiles.
// Each tile's Q-frag loads at tile start (L2-hot); sched_barrier(0) pins tile order so
// the compiler can't interleave bodies (acc liveness would blow the 128-VGPR cap).
// k pre-scaled by CEXP; softmax max-free; S^T = 16x16x32 A-fragment under k-bijection
// slot(lkg,e) = (e<4 ? lkg*4+e : 16+lkg*4+e-4); row-sums via ones-column MFMA.
__global__ __launch_bounds__(256, 4) void attn_kernel(
    const u16* __restrict__ qbuf, const u16* __restrict__ kvbuf, u16* __restrict__ obuf)
{
    __shared__ __align__(16) u16 Ks[256 * 32];   // 16384 B, XOR-swizzled contents
    __shared__ __align__(16) u16 Vt[32 * 264];   // 16896 B  Vt[d][k]
    const int logical = (blockIdx.x & 7) * 128 + (blockIdx.x >> 3);
    const int b = logical >> 7, h = (logical >> 4) & 7, qt4 = logical & 15;
    const int tid = threadIdx.x;
    const int wid = tid >> 6, lane = tid & 63;
    const int lrow = lane & 15, lkg = lane >> 4;

    // stage K: call c covers physical bytes [c*1024, +1024); lane's global source is the
    // swizzle-inverse of its linear dest slot.
    {
        const int loff = (lane * 16) ^ (((lane >> 3) & 7) << 4);
        const int rloc = loff >> 6, piece = (loff >> 4) & 3;
#pragma unroll
        for (int i = 0; i < 4; ++i) {
            const int c = wid * 4 + i;
            const u16* src = kvbuf + (size_t)(b * 256 + c * 16 + rloc) * 512 + h * 32 + piece * 8;
            gload16(src, Ks + c * 512);
        }
    }
    // stage V^T packed: thread t covers v-rows 2i,2i+1 (i=t&127), d-slice (t>>7)*16..+16
    {
        const int i = tid & 127, dbase = (tid >> 7) * 16;
        const u16* vs0 = kvbuf + (size_t)(b * 256 + 2 * i) * 512 + 256 + h * 32 + dbase;
        const u16* vs1 = vs0 + 512;
        ushort4 a0 = *(const ushort4*)(vs0);
        ushort4 a1 = *(const ushort4*)(vs0 + 4);
        ushort4 a2 = *(const ushort4*)(vs0 + 8);
        ushort4 a3 = *(const ushort4*)(vs0 + 12);
        ushort4 b0 = *(const ushort4*)(vs1);
        ushort4 b1 = *(const ushort4*)(vs1 + 4);
        ushort4 b2 = *(const ushort4*)(vs1 + 8);
        ushort4 b3 = *(const ushort4*)(vs1 + 12);
        unsigned* vw = (unsigned*)(Vt + (size_t)dbase * 264 + 2 * i);
#define VPACK(d, lo, hi) vw[(d) * 132] = ((unsigned)(hi) << 16) | (lo)
        VPACK(0,  a0.x, b0.x); VPACK(1,  a0.y, b0.y); VPACK(2,  a0.z, b0.z); VPACK(3,  a0.w, b0.w);
        VPACK(4,  a1.x, b1.x); VPACK(5,  a1.y, b1.y); VPACK(6,  a1.z, b1.z); VPACK(7,  a1.w, b1.w);
        VPACK(8,  a2.x, b2.x); VPACK(9,  a2.y, b2.y); VPACK(10, a2.z, b2.z); VPACK(11, a2.w, b2.w);
        VPACK(12, a3.x, b3.x); VPACK(13, a3.y, b3.y); VPACK(14, a3.z, b3.z); VPACK(15, a3.w, b3.w);
#undef VPACK
    }

    const int qcol = h * 32 + lkg * 8;
    const u16* qrow = qbuf + (size_t)(b * 4096 + qt4 * 256 + wid * 16 + lrow) * 256 + qcol;
    // tile-0 Q fragment loads under the staging latency
    bf16x8 qf = *(const bf16x8*)(qrow);

    // ones B-fragment for the row-sum MFMA (col-of-tile 0 only)
    bf16x8 onesf = {};
    if (lrow == 0) {
#pragma unroll
        for (int e = 0; e < 8; ++e) onesf[e] = (__bf16)1.0f;
    }

    __syncthreads();

    const int pbase = (lrow * 64 + lkg * 16) ^ (((lrow >> 1) & 7) << 4);

#define ATTN_TILE(TI, QF)                                                               \
    {                                                                                   \
        f32x4 acc[16];                                                                  \
        _Pragma("unroll")                                                               \
        for (int nf = 0; nf < 16; ++nf) acc[nf] = (f32x4){0.f, 0.f, 0.f, 0.f};          \
        _Pragma("unroll")                                                               \
        for (int nf = 0; nf < 16; ++nf) {                                               \
            bf16x8 kfr = *(const bf16x8*)((const char*)Ks + pbase + nf * 1024);         \
            acc[nf] = __builtin_amdgcn_mfma_f32_16x16x32_bf16(kfr, (QF), acc[nf], 0, 0, 0); \
        }                                                                               \
        bf16x8 pa8[8];                                                                  \
        _Pragma("unroll")                                                               \
        for (int nf2 = 0; nf2 < 8; ++nf2) {                                             \
            bf16x8 pv;                                                                  \
            _Pragma("unroll")                                                           \
            for (int half = 0; half < 2; ++half) {                                      \
                _Pragma("unroll")                                                       \
                for (int r = 0; r < 4; ++r)                                             \
                    pv[half * 4 + r] = (__bf16)exp2f(acc[2 * nf2 + half][r]);           \
            }                                                                           \
            pa8[nf2] = pv;                                                              \
        }                                                                               \
        f32x4 o0 = (f32x4){0.f, 0.f, 0.f, 0.f};                                         \
        f32x4 o1 = (f32x4){0.f, 0.f, 0.f, 0.f};                                         \
        f32x4 o2 = (f32x4){0.f, 0.f, 0.f, 0.f};                                         \
        _Pragma("unroll")                                                               \
        for (int nf2 = 0; nf2 < 8; ++nf2) {                                             \
            bf16x4 lo0 = *(const bf16x4*)(Vt + lrow * 264 + nf2 * 32 + lkg * 4);        \
            bf16x4 hi0 = *(const bf16x4*)(Vt + lrow * 264 + nf2 * 32 + 16 + lkg * 4);   \
            bf16x4 lo1 = *(const bf16x4*)(Vt + (16 + lrow) * 264 + nf2 * 32 + lkg * 4); \
            bf16x4 hi1 = *(const bf16x4*)(Vt + (16 + lrow) * 264 + nf2 * 32 + 16 + lkg * 4); \
            bf16x8 v0 = __builtin_shufflevector(lo0, hi0, 0, 1, 2, 3, 4, 5, 6, 7);      \
            bf16x8 v1 = __builtin_shufflevector(lo1, hi1, 0, 1, 2, 3, 4, 5, 6, 7);      \
            o0 = __builtin_amdgcn_mfma_f32_16x16x32_bf16(pa8[nf2], v0, o0, 0, 0, 0);    \
            o1 = __builtin_amdgcn_mfma_f32_16x16x32_bf16(pa8[nf2], v1, o1, 0, 0, 0);    \
            o2 = __builtin_amdgcn_mfma_f32_16x16x32_bf16(pa8[nf2], onesf, o2, 0, 0, 0); \
        }                                                                               \
        float invq[4];                                                                  \
        _Pragma("unroll")                                                               \
        for (int r = 0; r < 4; ++r)                                                     \
            invq[r] = __shfl(__builtin_amdgcn_rcpf(o2[r]), lane & 48);                  \
        const size_t obase = (size_t)(b * 4096 + qt4 * 256 + (TI) * 64 + wid * 16);     \
        _Pragma("unroll")                                                               \
        for (int r = 0; r < 4; ++r) {                                                   \
            u16* op = obuf + (obase + lkg * 4 + r) * 256 + h * 32 + lrow;               \
            op[0]  = f2bf(o0[r] * invq[r]);                                             \
            op[16] = f2bf(o1[r] * invq[r]);                                             \
        }                                                                               \
    }

    ATTN_TILE(0, qf)
    __builtin_amdgcn_sched_barrier(0);
    qf = *(const bf16x8*)(qrow + 64 * 256);
    ATTN_TILE(1, qf)
    __builtin_amdgcn_sched_barrier(0);
    qf = *(const bf16x8*)(qrow + 128 * 256);
    ATTN_TILE(2, qf)
    __builtin_amdgcn_sched_barrier(0);
    qf = *(const bf16x8*)(qrow + 192 * 256);
    ATTN_TILE(3, qf)
#undef ATTN_TILE
}

extern "C" void kernel_launch(void* const* d_in, const int* in_sizes, int n_in,
                              void* d_out, int out_size, void* d_ws, size_t ws_size,
                              hipStream_t stream)
{
    (void)in_sizes; (void)n_in; (void)out_size; (void)ws_size;
    const float* x   = (const float*)d_in[0];
    const float* qw  = (const float*)d_in[3];
    const float* qb  = (const float*)d_in[4];
    const float* kvw = (const float*)d_in[5];
    const float* kvb = (const float*)d_in[6];
    const float* srw = (const float*)d_in[7];
    const float* srb = (const float*)d_in[8];
    const float* lng = (const float*)d_in[9];
    const float* lnb = (const float*)d_in[10];
    const float* pw  = (const float*)d_in[11];
    const float* pb  = (const float*)d_in[12];

    char* ws = (char*)d_ws;
    u16*   xb      = (u16*)(ws + 0);          // 16.78 MB  x as bf16 [32768][256]
    u16*   att     = (u16*)(ws + 16777216);   // 16.78 MB  attention output bf16 [32768][256]
    float* part    = (float*)(ws + 33554432); //  8.39 MB  conv split-K partials [4][2048][256]
    u16*   wsr     = (u16*)(ws + 50331648);   //  2.10 MB
    u16*   wqb     = (u16*)(ws + 52428800);
    u16*   wkvb    = (u16*)(ws + 52559872);
    u16*   wpb     = (u16*)(ws + 52822016);
    u16*   xsr     = (u16*)(ws + 52953088);   //  1.05 MB  LN output bf16 [2048][256]
    u16*   kvo     = (u16*)(ws + 54001664);   //  2.10 MB  kv bf16 [2048][512] (k pre-scaled)
    u16*   qbuf    = (u16*)d_out;             // q bf16 [32768][256] in d_out scratch

    prep_all<<<8192, 256, 0, stream>>>(x, xb, qw, kvw, pw, srw, wqb, wkvb, wpb, wsr);
    fused_convq<<<640, 256, 0, stream>>>(xb, wsr, part, wqb, qb, qbuf);
    ln_kernel<<<2048, 256, 0, stream>>>(part, srb, lng, lnb, xsr);
    gemm64_kv<<<dim3(32, 8), 256, 0, stream>>>(xsr, wkvb, kvb, kvo);
    attn_kernel<<<1024, 256, 0, stream>>>(qbuf, kvo, att);
    gemm128<0, false><<<dim3(256, 2, 1), 256, 0, stream>>>(att, wpb, pb, d_out, 32768, 256, 256, 256);
}

// Round 22
// 83.872 us; speedup vs baseline: 1.0292x; 1.0292x over previous
//
#include <hip/hip_runtime.h>

typedef unsigned short u16;
typedef float f32x4 __attribute__((ext_vector_type(4)));
typedef __bf16 bf16x4 __attribute__((ext_vector_type(4)));
typedef __bf16 bf16x8 __attribute__((ext_vector_type(8)));

#define B_ 8
#define N_ 4096
#define C_ 256
#define NKV 256
// softmax scale folded into k: 1/sqrt(32) * log2(e)
#define CEXP 0.25506604f

__device__ inline u16 f2bf(float f) {
    union { float f; unsigned u; } v; v.f = f;
    unsigned r = v.u + 0x7FFF + ((v.u >> 16) & 1);
    return (u16)(r >> 16);
}

// async global->LDS, 16B per lane (dest linear-in-lane with 16B stride)
__device__ inline void gload16(const void* g, void* l) {
    __builtin_amdgcn_global_load_lds(
        (const __attribute__((address_space(1))) void*)g,
        (__attribute__((address_space(3))) void*)l, 16, 0, 0);
}

// ---------------- prep (merged): x -> bf16 xb; weights -> bf16 ----------------
__global__ __launch_bounds__(256) void prep_all(
    const float* __restrict__ x, u16* __restrict__ xb,
    const float* __restrict__ qw, const float* __restrict__ kvw,
    const float* __restrict__ pw, const float* __restrict__ srw,
    u16* __restrict__ wqb, u16* __restrict__ wkv, u16* __restrict__ wp, u16* __restrict__ wsr)
{
    // x part: one float4 per thread over 8192x256 threads
    size_t base = ((size_t)blockIdx.x * 256 + threadIdx.x) * 4;
    float4 v = *(const float4*)(x + base);
    ushort4 o;
    o.x = f2bf(v.x); o.y = f2bf(v.y); o.z = f2bf(v.z); o.w = f2bf(v.w);
    *(ushort4*)(xb + base) = o;

    // weight part (strided over the whole grid)
    int t = blockIdx.x * 256 + threadIdx.x;
    int stride = gridDim.x * 256;
    for (int i = t; i < 65536; i += stride) { wqb[i] = f2bf(qw[i]); wp[i] = f2bf(pw[i]); }
    for (int i = t; i < 131072; i += stride) wkv[i] = f2bf(kvw[i]);
    // wsr[o][(kh*4+kw)*256 + ci] = srw[o][ci][kh][kw]
    for (int i = t; i < 1048576; i += stride) {
        int oo = i >> 12, kk = i & 4095;
        int ci = kk & 255, khkw = kk >> 8;
        wsr[i] = f2bf(srw[(size_t)(oo * 256 + ci) * 16 + khkw]);
    }
}

// ---------------- 128x128 bf16 MFMA GEMM body, BK=64 double-depth staging ----------------
// out = A[M,K] @ Bt[N,K]^T (+bias). LDS per tile: two [128][32] sub-buffers (16 KB each
// operand). Chunk c (0..1023, 16B each) -> byte c*16 (LINEAR dest for global_load_lds);
// c>>9 selects the 32-k half (s), (c&511)>>2 the row, c&3 the 8-col piece. The (s,p2)
// split is folded into the per-chunk GLOBAL source. Halves barrier drains vs BK=32.
// kchunk must be a multiple of 64.
// OUTMODE: 0 = f32 out + bias, 1 = bf16 out + bias, 2 = f32 split-K partial (no bias)
// IM2COL: A is xb [B*N][C]; logical A-row = b*256 + hp*16 + wp, k = (kh*4+kw)*256 + c;
//         every 64-aligned k-span stays inside one (kh,kw) plane (k0,kk multiples of 64).
template<int OUTMODE, bool IM2COL>
__device__ __forceinline__ void gemm_body(
    u16* As, u16* Bs,
    const u16* __restrict__ A, const u16* __restrict__ Bt,
    const float* __restrict__ bias, void* __restrict__ outp,
    int M, int Nn, int K, int kchunk, int bm, int bn, int bz)
{
    const int tid = threadIdx.x;
    const int k0 = bz * kchunk;
    const int wid = tid >> 6, lane = tid & 63;
    const int wr = wid >> 1, wc = wid & 1;
    const int lrow = lane & 15, lkg = lane >> 4;

    f32x4 acc[4][4] = {};

    // 4 chunks per thread per operand: c_j = tid + 256*j
    const u16 *aS[4], *bS[4];
#pragma unroll
    for (int j = 0; j < 4; ++j) {
        const int c = tid + 256 * j;
        const int s = c >> 9, r = (c & 511) >> 2, p2 = c & 3;
        const int colo = s * 32 + p2 * 8;
        if constexpr (IM2COL) {
            const int g = bm * 128 + r;
            const int bb = g >> 8, p = g & 255;
            aS[j] = A + (size_t)(bb * 4096 + (p >> 4) * 256 + (p & 15) * 4) * 256 + colo;
        } else {
            aS[j] = A + (size_t)(bm * 128 + r) * K + k0 + colo;
        }
        bS[j] = Bt + (size_t)(bn * 128 + r) * K + k0 + colo;
    }

    for (int kk = 0; kk < kchunk; kk += 64) {
        int aoff;
        if constexpr (IM2COL) {
            const int K0 = k0 + kk;
            const int khkw = K0 >> 8;
            aoff = ((khkw >> 2) * 64 + (khkw & 3)) * 256 + (K0 & 255);
        } else {
            aoff = kk;
        }
#pragma unroll
        for (int j = 0; j < 4; ++j) {
            gload16(aS[j] + aoff, As + tid * 8 + j * 2048);
            gload16(bS[j] + kk,  Bs + tid * 8 + j * 2048);
        }
        __syncthreads();
#pragma unroll
        for (int ks = 0; ks < 2; ++ks) {
            bf16x8 af[4], bff[4];
#pragma unroll
            for (int i = 0; i < 4; ++i) {
                af[i]  = *(const bf16x8*)(As + ks * 4096 + (wr * 64 + i * 16 + lrow) * 32 + lkg * 8);
                bff[i] = *(const bf16x8*)(Bs + ks * 4096 + (wc * 64 + i * 16 + lrow) * 32 + lkg * 8);
            }
#pragma unroll
            for (int i = 0; i < 4; ++i)
#pragma unroll
                for (int j = 0; j < 4; ++j)
                    acc[i][j] = __builtin_amdgcn_mfma_f32_16x16x32_bf16(af[i], bff[j], acc[i][j], 0, 0, 0);
        }
        __syncthreads();
    }

    const int row0 = bm * 128 + wr * 64;
    const int col0 = bn * 128 + wc * 64;
    if constexpr (OUTMODE == 2) {
        float* o = (float*)outp + (size_t)bz * M * Nn;
#pragma unroll
        for (int i = 0; i < 4; ++i)
#pragma unroll
            for (int j = 0; j < 4; ++j)
#pragma unroll
                for (int reg = 0; reg < 4; ++reg)
                    o[(size_t)(row0 + i * 16 + lkg * 4 + reg) * Nn + col0 + j * 16 + lrow] = acc[i][j][reg];
    } else {
#pragma unroll
        for (int j = 0; j < 4; ++j) {
            const int col = col0 + j * 16 + lrow;
            float bv = bias[col];
#pragma unroll
            for (int i = 0; i < 4; ++i)
#pragma unroll
                for (int reg = 0; reg < 4; ++reg) {
                    const size_t idx = (size_t)(row0 + i * 16 + lkg * 4 + reg) * Nn + col;
                    const float val = acc[i][j][reg] + bv;
                    if constexpr (OUTMODE == 1) ((u16*)outp)[idx] = f2bf(val);
                    else                        ((float*)outp)[idx] = val;
                }
        }
    }
}

// standalone GEMM wrapper (output projection); 3 blocks/CU (96 KB LDS, ~110 VGPR < 170 cap)
template<int OUTMODE, bool IM2COL>
__global__ __launch_bounds__(256, 3) void gemm128(
    const u16* __restrict__ A, const u16* __restrict__ Bt,
    const float* __restrict__ bias, void* __restrict__ outp,
    int M, int Nn, int K, int kchunk)
{
    __shared__ __align__(16) u16 As[128 * 64];
    __shared__ __align__(16) u16 Bs[128 * 64];
    gemm_body<OUTMODE, IM2COL>(As, Bs, A, Bt, bias, outp, M, Nn, K, kchunk,
                               blockIdx.x, blockIdx.y, blockIdx.z);
}

// ---------------- fused launch: conv GEMM (split-K x8, im2col) + q projection -------------
// ids 0..255: conv (16 bm x 2 bn x 8 z, K=512 each). ids 256..767: q proj (256 bm x 2 bn).
// No cross-block sync (round-12 lesson: dispatch order is undefined).
__global__ __launch_bounds__(256, 3) void fused_convq(
    const u16* __restrict__ xb, const u16* __restrict__ wsr, float* __restrict__ part,
    const u16* __restrict__ wqb, const float* __restrict__ qb, u16* __restrict__ qbuf)
{
    __shared__ __align__(16) u16 As[128 * 64];
    __shared__ __align__(16) u16 Bs[128 * 64];
    const int id = blockIdx.x;
    if (id < 256) {
        const int z = id & 7, t = id >> 3;
        gemm_body<2, true>(As, Bs, xb, wsr, nullptr, part,
                           2048, 256, 4096, 512, t >> 1, t & 1, z);
    } else {
        const int qid = id - 256;
        gemm_body<1, false>(As, Bs, xb, wqb, qb, qbuf,
                            32768, 256, 256, 256, qid >> 1, qid & 1, 0);
    }
}

// ---------------- LN over conv partial sums: xsr = LN(sum_z part + sr_b) -> bf16 ----------------
__global__ __launch_bounds__(256) void ln_kernel(
    const float* __restrict__ part, const float* __restrict__ srb,
    const float* __restrict__ g, const float* __restrict__ bb, u16* __restrict__ out)
{
    const int row = blockIdx.x, c = threadIdx.x;
    const size_t idx = (size_t)row * 256 + c;
    float v = srb[c];
#pragma unroll
    for (int z = 0; z < 8; ++z) v += part[idx + (size_t)z * 524288];
    float s = v;
#pragma unroll
    for (int m = 1; m < 64; m <<= 1) s += __shfl_xor(s, m);
    __shared__ float red[4];
    if ((c & 63) == 0) red[c >> 6] = s;
    __syncthreads();
    float tot = red[0] + red[1] + red[2] + red[3];
    float mu = tot * (1.0f / 256.0f);
    float d = v - mu;
    float s2 = d * d;
#pragma unroll
    for (int m = 1; m < 64; m <<= 1) s2 += __shfl_xor(s2, m);
    __syncthreads();
    if ((c & 63) == 0) red[c >> 6] = s2;
    __syncthreads();
    float var = (red[0] + red[1] + red[2] + red[3]) * (1.0f / 256.0f);
    out[idx] = f2bf(d * rsqrtf(var + 1e-5f) * g[c] + bb[c]);
}

// ---------------- kv projection: 64x64 tiles, BK=64 staging, k-half pre-scaled ------------
// grid (32, 8) = 256 blocks. Two [64][32] sub-buffers per operand; chunk c (0..511) ->
// byte c*16 linear; c>>8 = 32-k half, (c&255)>>2 = row, c&3 = piece.
__global__ __launch_bounds__(256, 2) void gemm64_kv(
    const u16* __restrict__ A, const u16* __restrict__ Bt,
    const float* __restrict__ bias, u16* __restrict__ outp)
{
    __shared__ __align__(16) u16 As[64 * 64];
    __shared__ __align__(16) u16 Bs[64 * 64];
    const int tid = threadIdx.x, bm = blockIdx.x, bn = blockIdx.y;
    const int wid = tid >> 6, lane = tid & 63;
    const int wr = wid >> 1, wc = wid & 1;
    const int lrow = lane & 15, lkg = lane >> 4;

    f32x4 acc[2][2] = {};
    const u16 *aS[2], *bS[2];
#pragma unroll
    for (int j = 0; j < 2; ++j) {
        const int c = tid + 256 * j;
        const int s = c >> 8, r = (c & 255) >> 2, p2 = c & 3;
        const int colo = s * 32 + p2 * 8;
        aS[j] = A  + (size_t)(bm * 64 + r) * 256 + colo;
        bS[j] = Bt + (size_t)(bn * 64 + r) * 256 + colo;
    }

    for (int kk = 0; kk < 256; kk += 64) {
#pragma unroll
        for (int j = 0; j < 2; ++j) {
            gload16(aS[j] + kk, As + tid * 8 + j * 2048);
            gload16(bS[j] + kk, Bs + tid * 8 + j * 2048);
        }
        __syncthreads();
#pragma unroll
        for (int ks = 0; ks < 2; ++ks) {
            bf16x8 af[2], bf2[2];
#pragma unroll
            for (int i = 0; i < 2; ++i) {
                af[i]  = *(const bf16x8*)(As + ks * 2048 + (wr * 32 + i * 16 + lrow) * 32 + lkg * 8);
                bf2[i] = *(const bf16x8*)(Bs + ks * 2048 + (wc * 32 + i * 16 + lrow) * 32 + lkg * 8);
            }
#pragma unroll
            for (int i = 0; i < 2; ++i)
#pragma unroll
                for (int j = 0; j < 2; ++j)
                    acc[i][j] = __builtin_amdgcn_mfma_f32_16x16x32_bf16(af[i], bf2[j], acc[i][j], 0, 0, 0);
        }
        __syncthreads();
    }

    const int row0 = bm * 64 + wr * 32;
    const int col0 = bn * 64 + wc * 32;
#pragma unroll
    for (int j = 0; j < 2; ++j) {
        const int col = col0 + j * 16 + lrow;
        const float bv = bias[col];
        const float sc = (col < 256) ? CEXP : 1.0f;
#pragma unroll
        for (int i = 0; i < 2; ++i)
#pragma unroll
            for (int reg = 0; reg < 4; ++reg)
                outp[(size_t)(row0 + i * 16 + lkg * 4 + reg) * 512 + col] =
                    f2bf((acc[i][j][reg] + bv) * sc);
    }
}

// ---------------- fused attention v10: 4 q-tiles per staged K/V; XCD-aware 1D grid --------
// grid 1024 = exactly one residency wave (256 CU x 4 blocks). logical = (bid&7)*128+bid>>3
// (each XCD owns one batch b; 1024%8==0). Per block: stage K[256][32] (XOR-swizzled via
// pre-swizzled global source) + V^T[32][264] ONCE, then 4 sequential 64-row q-tiles.
// Each tile's Q-frag loads at tile start (L2-hot); sched_barrier(0) pins tile order so
// the compiler can't interleave bodies (acc liveness would blow the 128-VGPR cap).
// k pre-scaled by CEXP; softmax max-free; S^T = 16x16x32 A-fragment under k-bijection
// slot(lkg,e) = (e<4 ? lkg*4+e : 16+lkg*4+e-4); row-sums via ones-column MFMA.
__global__ __launch_bounds__(256, 4) void attn_kernel(
    const u16* __restrict__ qbuf, const u16* __restrict__ kvbuf, u16* __restrict__ obuf)
{
    __shared__ __align__(16) u16 Ks[256 * 32];   // 16384 B, XOR-swizzled contents
    __shared__ __align__(16) u16 Vt[32 * 264];   // 16896 B  Vt[d][k]
    const int logical = (blockIdx.x & 7) * 128 + (blockIdx.x >> 3);
    const int b = logical >> 7, h = (logical >> 4) & 7, qt4 = logical & 15;
    const int tid = threadIdx.x;
    const int wid = tid >> 6, lane = tid & 63;
    const int lrow = lane & 15, lkg = lane >> 4;

    // stage K: call c covers physical bytes [c*1024, +1024); lane's global source is the
    // swizzle-inverse of its linear dest slot.
    {
        const int loff = (lane * 16) ^ (((lane >> 3) & 7) << 4);
        const int rloc = loff >> 6, piece = (loff >> 4) & 3;
#pragma unroll
        for (int i = 0; i < 4; ++i) {
            const int c = wid * 4 + i;
            const u16* src = kvbuf + (size_t)(b * 256 + c * 16 + rloc) * 512 + h * 32 + piece * 8;
            gload16(src, Ks + c * 512);
        }
    }
    // stage V^T packed: thread t covers v-rows 2i,2i+1 (i=t&127), d-slice (t>>7)*16..+16
    {
        const int i = tid & 127, dbase = (tid >> 7) * 16;
        const u16* vs0 = kvbuf + (size_t)(b * 256 + 2 * i) * 512 + 256 + h * 32 + dbase;
        const u16* vs1 = vs0 + 512;
        ushort4 a0 = *(const ushort4*)(vs0);
        ushort4 a1 = *(const ushort4*)(vs0 + 4);
        ushort4 a2 = *(const ushort4*)(vs0 + 8);
        ushort4 a3 = *(const ushort4*)(vs0 + 12);
        ushort4 b0 = *(const ushort4*)(vs1);
        ushort4 b1 = *(const ushort4*)(vs1 + 4);
        ushort4 b2 = *(const ushort4*)(vs1 + 8);
        ushort4 b3 = *(const ushort4*)(vs1 + 12);
        unsigned* vw = (unsigned*)(Vt + (size_t)dbase * 264 + 2 * i);
#define VPACK(d, lo, hi) vw[(d) * 132] = ((unsigned)(hi) << 16) | (lo)
        VPACK(0,  a0.x, b0.x); VPACK(1,  a0.y, b0.y); VPACK(2,  a0.z, b0.z); VPACK(3,  a0.w, b0.w);
        VPACK(4,  a1.x, b1.x); VPACK(5,  a1.y, b1.y); VPACK(6,  a1.z, b1.z); VPACK(7,  a1.w, b1.w);
        VPACK(8,  a2.x, b2.x); VPACK(9,  a2.y, b2.y); VPACK(10, a2.z, b2.z); VPACK(11, a2.w, b2.w);
        VPACK(12, a3.x, b3.x); VPACK(13, a3.y, b3.y); VPACK(14, a3.z, b3.z); VPACK(15, a3.w, b3.w);
#undef VPACK
    }

    const int qcol = h * 32 + lkg * 8;
    const u16* qrow = qbuf + (size_t)(b * 4096 + qt4 * 256 + wid * 16 + lrow) * 256 + qcol;
    // tile-0 Q fragment loads under the staging latency
    bf16x8 qf = *(const bf16x8*)(qrow);

    // ones B-fragment for the row-sum MFMA (col-of-tile 0 only)
    bf16x8 onesf = {};
    if (lrow == 0) {
#pragma unroll
        for (int e = 0; e < 8; ++e) onesf[e] = (__bf16)1.0f;
    }

    __syncthreads();

    const int pbase = (lrow * 64 + lkg * 16) ^ (((lrow >> 1) & 7) << 4);

#define ATTN_TILE(TI, QF)                                                               \
    {                                                                                   \
        f32x4 acc[16];                                                                  \
        _Pragma("unroll")                                                               \
        for (int nf = 0; nf < 16; ++nf) acc[nf] = (f32x4){0.f, 0.f, 0.f, 0.f};          \
        _Pragma("unroll")                                                               \
        for (int nf = 0; nf < 16; ++nf) {                                               \
            bf16x8 kfr = *(const bf16x8*)((const char*)Ks + pbase + nf * 1024);         \
            acc[nf] = __builtin_amdgcn_mfma_f32_16x16x32_bf16(kfr, (QF), acc[nf], 0, 0, 0); \
        }                                                                               \
        bf16x8 pa8[8];                                                                  \
        _Pragma("unroll")                                                               \
        for (int nf2 = 0; nf2 < 8; ++nf2) {                                             \
            bf16x8 pv;                                                                  \
            _Pragma("unroll")                                                           \
            for (int half = 0; half < 2; ++half) {                                      \
                _Pragma("unroll")                                                       \
                for (int r = 0; r < 4; ++r)                                             \
                    pv[half * 4 + r] = (__bf16)exp2f(acc[2 * nf2 + half][r]);           \
            }                                                                           \
            pa8[nf2] = pv;                                                              \
        }                                                                               \
        f32x4 o0 = (f32x4){0.f, 0.f, 0.f, 0.f};                                         \
        f32x4 o1 = (f32x4){0.f, 0.f, 0.f, 0.f};                                         \
        f32x4 o2 = (f32x4){0.f, 0.f, 0.f, 0.f};                                         \
        _Pragma("unroll")                                                               \
        for (int nf2 = 0; nf2 < 8; ++nf2) {                                             \
            bf16x4 lo0 = *(const bf16x4*)(Vt + lrow * 264 + nf2 * 32 + lkg * 4);        \
            bf16x4 hi0 = *(const bf16x4*)(Vt + lrow * 264 + nf2 * 32 + 16 + lkg * 4);   \
            bf16x4 lo1 = *(const bf16x4*)(Vt + (16 + lrow) * 264 + nf2 * 32 + lkg * 4); \
            bf16x4 hi1 = *(const bf16x4*)(Vt + (16 + lrow) * 264 + nf2 * 32 + 16 + lkg * 4); \
            bf16x8 v0 = __builtin_shufflevector(lo0, hi0, 0, 1, 2, 3, 4, 5, 6, 7);      \
            bf16x8 v1 = __builtin_shufflevector(lo1, hi1, 0, 1, 2, 3, 4, 5, 6, 7);      \
            o0 = __builtin_amdgcn_mfma_f32_16x16x32_bf16(pa8[nf2], v0, o0, 0, 0, 0);    \
            o1 = __builtin_amdgcn_mfma_f32_16x16x32_bf16(pa8[nf2], v1, o1, 0, 0, 0);    \
            o2 = __builtin_amdgcn_mfma_f32_16x16x32_bf16(pa8[nf2], onesf, o2, 0, 0, 0); \
        }                                                                               \
        float invq[4];                                                                  \
        _Pragma("unroll")                                                               \
        for (int r = 0; r < 4; ++r)                                                     \
            invq[r] = __shfl(__builtin_amdgcn_rcpf(o2[r]), lane & 48);                  \
        const size_t obase = (size_t)(b * 4096 + qt4 * 256 + (TI) * 64 + wid * 16);     \
        _Pragma("unroll")                                                               \
        for (int r = 0; r < 4; ++r) {                                                   \
            u16* op = obuf + (obase + lkg * 4 + r) * 256 + h * 32 + lrow;               \
            op[0]  = f2bf(o0[r] * invq[r]);                                             \
            op[16] = f2bf(o1[r] * invq[r]);                                             \
        }                                                                               \
    }

    ATTN_TILE(0, qf)
    __builtin_amdgcn_sched_barrier(0);
    qf = *(const bf16x8*)(qrow + 64 * 256);
    ATTN_TILE(1, qf)
    __builtin_amdgcn_sched_barrier(0);
    qf = *(const bf16x8*)(qrow + 128 * 256);
    ATTN_TILE(2, qf)
    __builtin_amdgcn_sched_barrier(0);
    qf = *(const bf16x8*)(qrow + 192 * 256);
    ATTN_TILE(3, qf)
#undef ATTN_TILE
}

extern "C" void kernel_launch(void* const* d_in, const int* in_sizes, int n_in,
                              void* d_out, int out_size, void* d_ws, size_t ws_size,
                              hipStream_t stream)
{
    (void)in_sizes; (void)n_in; (void)out_size; (void)ws_size;
    const float* x   = (const float*)d_in[0];
    const float* qw  = (const float*)d_in[3];
    const float* qb  = (const float*)d_in[4];
    const float* kvw = (const float*)d_in[5];
    const float* kvb = (const float*)d_in[6];
    const float* srw = (const float*)d_in[7];
    const float* srb = (const float*)d_in[8];
    const float* lng = (const float*)d_in[9];
    const float* lnb = (const float*)d_in[10];
    const float* pw  = (const float*)d_in[11];
    const float* pb  = (const float*)d_in[12];

    char* ws = (char*)d_ws;
    u16*   xb      = (u16*)(ws + 0);          // 16.78 MB  x as bf16 [32768][256]
    u16*   att     = (u16*)(ws + 16777216);   // 16.78 MB  attention output bf16 [32768][256]
    float* part    = (float*)(ws + 33554432); // 16.78 MB  conv split-K partials [8][2048][256]
    u16*   wsr     = (u16*)(ws + 50331648);   //  2.10 MB
    u16*   wqb     = (u16*)(ws + 52428800);
    u16*   wkvb    = (u16*)(ws + 52559872);
    u16*   wpb     = (u16*)(ws + 52822016);
    u16*   xsr     = (u16*)(ws + 52953088);   //  1.05 MB  LN output bf16 [2048][256]
    u16*   kvo     = (u16*)(ws + 54001664);   //  2.10 MB  kv bf16 [2048][512] (k pre-scaled)
    u16*   qbuf    = (u16*)d_out;             // q bf16 [32768][256] in d_out scratch

    prep_all<<<8192, 256, 0, stream>>>(x, xb, qw, kvw, pw, srw, wqb, wkvb, wpb, wsr);
    fused_convq<<<768, 256, 0, stream>>>(xb, wsr, part, wqb, qb, qbuf);
    ln_kernel<<<2048, 256, 0, stream>>>(part, srb, lng, lnb, xsr);
    gemm64_kv<<<dim3(32, 8), 256, 0, stream>>>(xsr, wkvb, kvb, kvo);
    attn_kernel<<<1024, 256, 0, stream>>>(qbuf, kvo, att);
    gemm128<0, false><<<dim3(256, 2, 1), 256, 0, stream>>>(att, wpb, pb, d_out, 32768, 256, 256, 256);
}